// Round 3
// baseline (1328.664 us; speedup 1.0000x reference)
//
#include <hip/hip_runtime.h>
#include <hip/hip_bf16.h>

#define N_IN_F 384
#define N_HID  128
#define N_OUT  64

union U8 { uint4 v; unsigned short u[8]; };

__device__ __forceinline__ float bfu2f(unsigned short s){
    union { unsigned i; float f; } c; c.i = ((unsigned)s) << 16; return c.f;
}
__device__ __forceinline__ unsigned short f2bfu(float f){
    __hip_bfloat16 h = __float2bfloat16(f);
    union { __hip_bfloat16 h; unsigned short u; } c; c.h = h; return c.u;
}

// fm == 1: tensor is bf16; fm == 0: tensor is float32
__device__ __forceinline__ float loadS(const void* p, size_t i, int fm){
    return fm ? bfu2f(((const unsigned short*)p)[i]) : ((const float*)p)[i];
}
__device__ __forceinline__ void load8(const void* p, size_t i, int fm, float o[8]){
    if (fm){
        U8 u; u.v = *(const uint4*)((const unsigned short*)p + i);
        #pragma unroll
        for (int q = 0; q < 8; q++) o[q] = bfu2f(u.u[q]);
    } else {
        float4 a = *(const float4*)((const float*)p + i);
        float4 b = *(const float4*)((const float*)p + i + 4);
        o[0]=a.x; o[1]=a.y; o[2]=a.z; o[3]=a.w;
        o[4]=b.x; o[5]=b.y; o[6]=b.z; o[7]=b.w;
    }
}

// ---------------- dtype probes ----------------
// modep[0]: 1 if edge_index is int64, 0 if int32
// modep[1]: 1 if float tensors are bf16, 0 if float32
__global__ void k_detect_all(const int* __restrict__ ei, const unsigned* __restrict__ xw,
                             int* __restrict__ modep){
    int lane = threadIdx.x & 63;
    int zi = 0;
    if (lane < 32) zi = ei[2*lane + 1];
    int cnt = 0;
    #pragma unroll
    for (int q = 0; q < 8; q++){
        unsigned w = xw[lane*8 + q];
        unsigned elo = (w >> 7) & 0xff;
        cnt += (elo >= 118 && elo <= 134) ? 1 : 0;
    }
    #pragma unroll
    for (int m = 32; m; m >>= 1){ zi |= __shfl_xor(zi, m, 64); cnt += __shfl_xor(cnt, m, 64); }
    if (lane == 0 && blockIdx.x == 0){
        modep[0] = (zi == 0) ? 1 : 0;
        modep[1] = (cnt >= 256) ? 1 : 0;
    }
}

__device__ __forceinline__ int edge_src(const int* ei, int e, int i, int mode){
    return mode ? ei[2*(size_t)i] : ei[i];
}
__device__ __forceinline__ int edge_dst(const int* ei, int e, int i, int mode){
    return mode ? ei[2*(size_t)e + 2*(size_t)i] : ei[(size_t)e + i];
}

// ---------------- LN1 row stats ----------------
__global__ __launch_bounds__(256) void k_ln_stats(
    const void* __restrict__ x, const int* __restrict__ fmp,
    float* __restrict__ mean_, float* __restrict__ rstd_, int n)
{
    int fm   = fmp[0];
    int lane = threadIdx.x & 63;
    int row  = blockIdx.x * 4 + (threadIdx.x >> 6);
    if (row >= n) return;
    float s = 0.f, s2 = 0.f;
    #pragma unroll
    for (int j = 0; j < 3; j++){
        size_t idx = (size_t)row * N_IN_F + j*128 + lane*2;
        float a, b;
        if (fm){
            unsigned u = *(const unsigned*)((const unsigned short*)x + idx);
            a = bfu2f((unsigned short)(u & 0xffff));
            b = bfu2f((unsigned short)(u >> 16));
        } else {
            float2 f = *(const float2*)((const float*)x + idx);
            a = f.x; b = f.y;
        }
        s += a + b; s2 += a*a + b*b;
    }
    #pragma unroll
    for (int m = 32; m; m >>= 1){ s += __shfl_xor(s, m, 64); s2 += __shfl_xor(s2, m, 64); }
    if (lane == 0){
        float mu  = s * (1.f/384.f);
        float var = fmaxf(s2 * (1.f/384.f) - mu*mu, 0.f);
        mean_[row] = mu;
        rstd_[row] = rsqrtf(var + 1e-5f);
    }
}

// ---------------- CSR build ----------------
__global__ void k_hist(const int* __restrict__ ei, int e, int n, const int* __restrict__ modep,
                       int* __restrict__ deg){
    int i = blockIdx.x * 256 + threadIdx.x;
    if (i >= e) return;
    int mode = modep[0];
    int d = edge_dst(ei, e, i, mode);
    if ((unsigned)d >= (unsigned)n) return;
    atomicAdd(&deg[d], 1);
}

__global__ __launch_bounds__(1024) void k_scan_all(
    int* __restrict__ deg, int n, int* __restrict__ rowoff)
{
    __shared__ int s[1024];
    __shared__ int carry;
    int t = threadIdx.x;
    if (t == 0) carry = 0;
    __syncthreads();
    for (int base = 0; base < n; base += 1024){
        int i = base + t;
        int v = (i < n) ? deg[i] : 0;
        s[t] = v;
        __syncthreads();
        for (int off = 1; off < 1024; off <<= 1){
            int tmp = (t >= off) ? s[t - off] : 0;
            __syncthreads();
            s[t] += tmp;
            __syncthreads();
        }
        int incl = s[t];
        int excl = incl - v + carry;
        if (i < n){ rowoff[i] = excl; deg[i] = excl; }
        __syncthreads();
        if (t == 1023) carry += incl;
        __syncthreads();
    }
    if (t == 0) rowoff[n] = carry;
}

__global__ void k_scatter(const int* __restrict__ ei, const void* __restrict__ ea,
                          int e, int n, const int* __restrict__ modep,
                          int* __restrict__ cursor, int* __restrict__ col,
                          float* __restrict__ wgt)
{
    int i = blockIdx.x * 256 + threadIdx.x;
    if (i >= e) return;
    int mode = modep[0], fm = modep[1];
    int d = edge_dst(ei, e, i, mode);
    if ((unsigned)d >= (unsigned)n) return;
    int s = edge_src(ei, e, i, mode);
    if ((unsigned)s >= (unsigned)n) s = 0;
    int pos = atomicAdd(&cursor[d], 1);
    if ((unsigned)pos >= (unsigned)e) return;
    col[pos] = s;
    wgt[pos] = loadS(ea, i, fm);
}

// ---------------- GEMM1: fused LN1 + fc1 ----------------
__global__ __launch_bounds__(256) void k_gemm1(
    const void* __restrict__ x, const int* __restrict__ fmp,
    const float* __restrict__ mean_, const float* __restrict__ rstd_,
    const void* __restrict__ g, const void* __restrict__ b,
    const void* __restrict__ W,      // [128,384]
    const void* __restrict__ bias,   // [128]
    __hip_bfloat16* __restrict__ out, int n)
{
    __shared__ float As[32][68];
    __shared__ float Bs[32][128];
    __shared__ float Gs[N_IN_F], Bb[N_IN_F];

    int fm = fmp[0];
    int t = threadIdx.x;
    for (int i = t; i < N_IN_F; i += 256){
        Gs[i] = loadS(g, i, fm);
        Bb[i] = loadS(b, i, fm);
    }

    int i0   = blockIdx.x * 64;
    int arow = t >> 2, aseg = t & 3;
    int bj   = t >> 1, bsg  = t & 1;
    int tx   = t & 15, r0   = (t >> 4) * 4;

    int gi = i0 + arow;
    float m = 0.f, rs = 0.f;
    if (gi < n){ m = mean_[gi]; rs = rstd_[gi]; }

    float acc[4][8] = {};
    __syncthreads();

    for (int k0 = 0; k0 < N_IN_F; k0 += 32){
        float av8[8] = {};
        if (gi < n) load8(x, (size_t)gi*N_IN_F + k0 + aseg*8, fm, av8);
        #pragma unroll
        for (int j = 0; j < 8; j++){
            int kk = aseg*8 + j;
            As[kk][arow] = (av8[j] - m) * rs * Gs[k0+kk] + Bb[k0+kk];
        }
        {
            float w0[8], w1[8];
            size_t wb = (size_t)bj*N_IN_F + k0 + bsg*16;
            load8(W, wb,     fm, w0);
            load8(W, wb + 8, fm, w1);
            #pragma unroll
            for (int q = 0; q < 8; q++){
                Bs[bsg*16 + q][bj]     = w0[q];
                Bs[bsg*16 + 8 + q][bj] = w1[q];
            }
        }
        __syncthreads();
        #pragma unroll
        for (int kk = 0; kk < 32; kk++){
            float av[4]; *(float4*)av = *(const float4*)&As[kk][r0];
            float bv[8];
            *(float4*)&bv[0] = *(const float4*)&Bs[kk][tx*4];
            *(float4*)&bv[4] = *(const float4*)&Bs[kk][64 + tx*4];
            #pragma unroll
            for (int a = 0; a < 4; a++)
                #pragma unroll
                for (int c = 0; c < 8; c++)
                    acc[a][c] += av[a] * bv[c];
        }
        __syncthreads();
    }

    float bia[8];
    #pragma unroll
    for (int q = 0; q < 4; q++){
        bia[q]   = loadS(bias, tx*4 + q, fm);
        bia[4+q] = loadS(bias, 64 + tx*4 + q, fm);
    }
    #pragma unroll
    for (int a = 0; a < 4; a++){
        int i = i0 + r0 + a;
        if (i >= n) continue;
        union { unsigned short u[4]; uint2 v; } P0, P1;
        #pragma unroll
        for (int q = 0; q < 4; q++){
            P0.u[q] = f2bfu(acc[a][q]   + bia[q]);
            P1.u[q] = f2bfu(acc[a][4+q] + bia[4+q]);
        }
        *(uint2*)(out + (size_t)i*128 + tx*4)      = P0.v;
        *(uint2*)(out + (size_t)i*128 + 64 + tx*4) = P1.v;
    }
}

// ---------------- CSR aggregation ----------------
__global__ __launch_bounds__(256) void k_agg(
    const int* __restrict__ rowoff, const int* __restrict__ col,
    const float* __restrict__ wgt,
    const __hip_bfloat16* __restrict__ src_mat,  // [n,128] (internal bf16)
    __hip_bfloat16* __restrict__ out, int n, int eTot)
{
    int lane = threadIdx.x & 63;
    int d    = blockIdx.x * 4 + (threadIdx.x >> 6);
    if (d >= n) return;
    int e0 = rowoff[d], e1 = rowoff[d+1];
    e0 = max(0, min(e0, eTot));
    e1 = max(e0, min(e1, eTot));
    float ax = 0.f, ay = 0.f;
    for (int e = e0; e < e1; e++){
        int s = col[e];
        if ((unsigned)s >= (unsigned)n) s = 0;
        float wv = wgt[e];
        unsigned u = *(const unsigned*)(src_mat + (size_t)s*128 + lane*2);
        ax += wv * bfu2f((unsigned short)(u & 0xffff));
        ay += wv * bfu2f((unsigned short)(u >> 16));
    }
    unsigned pk = ((unsigned)f2bfu(ay) << 16) | (unsigned)f2bfu(ax);
    *(unsigned*)(out + (size_t)d*128 + lane*2) = pk;
}

// ---------------- fused conv GEMM ----------------
template<int BNv>
__global__ __launch_bounds__(256) void k_gemm_conv(
    const __hip_bfloat16* __restrict__ A1,   // agg  [n,128] (internal bf16)
    const __hip_bfloat16* __restrict__ A2,   // root [n,128] (internal bf16)
    const void* __restrict__ W1,             // wrel [BNv,128]
    const void* __restrict__ W2,             // wroot[BNv,128]
    const void* __restrict__ bias,           // [BNv]
    const int* __restrict__ fmp,
    __hip_bfloat16* __restrict__ out,        // [n,BNv]
    int n)
{
    constexpr int NCOL = BNv / 16;
    __shared__ float As1[32][68], As2[32][68];
    __shared__ float Bs1[32][BNv], Bs2[32][BNv];

    int fm = fmp[0];
    int t = threadIdx.x;
    int i0   = blockIdx.x * 64;
    int arow = t >> 2, aseg = t & 3;
    int tx   = t & 15, r0   = (t >> 4) * 4;
    int gi = i0 + arow;

    float acc[4][NCOL] = {};

    for (int k0 = 0; k0 < 128; k0 += 32){
        U8 a1, a2; a1.v = make_uint4(0,0,0,0); a2.v = a1.v;
        if (gi < n){
            a1.v = *(const uint4*)(A1 + (size_t)gi*128 + k0 + aseg*8);
            a2.v = *(const uint4*)(A2 + (size_t)gi*128 + k0 + aseg*8);
        }
        #pragma unroll
        for (int j = 0; j < 8; j++){
            As1[aseg*8 + j][arow] = bfu2f(a1.u[j]);
            As2[aseg*8 + j][arow] = bfu2f(a2.u[j]);
        }
        if constexpr (BNv == 128){
            int j = t >> 1, sg = t & 1;
            size_t wb = (size_t)j*128 + k0 + sg*16;
            float x0[8], x1[8], y0[8], y1[8];
            load8(W1, wb, fm, x0); load8(W1, wb + 8, fm, x1);
            load8(W2, wb, fm, y0); load8(W2, wb + 8, fm, y1);
            #pragma unroll
            for (int q = 0; q < 8; q++){
                Bs1[sg*16 + q][j]     = x0[q];
                Bs1[sg*16 + 8 + q][j] = x1[q];
                Bs2[sg*16 + q][j]     = y0[q];
                Bs2[sg*16 + 8 + q][j] = y1[q];
            }
        } else {
            int j = t >> 2, sg = t & 3;
            size_t wb = (size_t)j*128 + k0 + sg*8;
            float x0[8], y0[8];
            load8(W1, wb, fm, x0); load8(W2, wb, fm, y0);
            #pragma unroll
            for (int q = 0; q < 8; q++){
                Bs1[sg*8 + q][j] = x0[q];
                Bs2[sg*8 + q][j] = y0[q];
            }
        }
        __syncthreads();
        #pragma unroll
        for (int kk = 0; kk < 32; kk++){
            float av1[4], av2[4];
            *(float4*)av1 = *(const float4*)&As1[kk][r0];
            *(float4*)av2 = *(const float4*)&As2[kk][r0];
            if constexpr (BNv == 128){
                float bv1[8], bv2[8];
                *(float4*)&bv1[0] = *(const float4*)&Bs1[kk][tx*4];
                *(float4*)&bv1[4] = *(const float4*)&Bs1[kk][64 + tx*4];
                *(float4*)&bv2[0] = *(const float4*)&Bs2[kk][tx*4];
                *(float4*)&bv2[4] = *(const float4*)&Bs2[kk][64 + tx*4];
                #pragma unroll
                for (int a = 0; a < 4; a++)
                    #pragma unroll
                    for (int c = 0; c < 8; c++)
                        acc[a][c] += av1[a]*bv1[c] + av2[a]*bv2[c];
            } else {
                float bv1[4], bv2[4];
                *(float4*)bv1 = *(const float4*)&Bs1[kk][tx*4];
                *(float4*)bv2 = *(const float4*)&Bs2[kk][tx*4];
                #pragma unroll
                for (int a = 0; a < 4; a++)
                    #pragma unroll
                    for (int c = 0; c < 4; c++)
                        acc[a][c] += av1[a]*bv1[c] + av2[a]*bv2[c];
            }
        }
        __syncthreads();
    }

    float bia[NCOL];
    #pragma unroll
    for (int q = 0; q < 4; q++) bia[q] = loadS(bias, tx*4 + q, fm);
    if constexpr (BNv == 128){
        #pragma unroll
        for (int q = 0; q < 4; q++) bia[4+q] = loadS(bias, 64 + tx*4 + q, fm);
    }
    #pragma unroll
    for (int a = 0; a < 4; a++){
        int i = i0 + r0 + a;
        if (i >= n) continue;
        union { unsigned short u[4]; uint2 v; } P0;
        #pragma unroll
        for (int q = 0; q < 4; q++){
            float vv = acc[a][q] + bia[q];
            vv = (vv >= 0.f) ? vv : 0.01f * vv;
            P0.u[q] = f2bfu(vv);
        }
        *(uint2*)(out + (size_t)i*BNv + tx*4) = P0.v;
        if constexpr (BNv == 128){
            union { unsigned short u[4]; uint2 v; } P1;
            #pragma unroll
            for (int q = 0; q < 4; q++){
                float vv = acc[a][4+q] + bia[4+q];
                vv = (vv >= 0.f) ? vv : 0.01f * vv;
                P1.u[q] = f2bfu(vv);
            }
            *(uint2*)(out + (size_t)i*BNv + 64 + tx*4) = P1.v;
        }
    }
}

// ---------------- final: LN2 + fc2 (64 -> 2) ----------------
__global__ __launch_bounds__(256) void k_final(
    const __hip_bfloat16* __restrict__ g2,   // [n,64] internal bf16
    const void* __restrict__ gam, const void* __restrict__ bet,
    const void* __restrict__ W,    // [2,64]
    const void* __restrict__ bias, // [2]
    const int* __restrict__ fmp,
    void* __restrict__ out, int n)
{
    int fm   = fmp[0];
    int lane = threadIdx.x & 63;
    int i    = blockIdx.x * 4 + (threadIdx.x >> 6);
    if (i >= n) return;
    float z = __bfloat162float(g2[(size_t)i*64 + lane]);
    float s = z, s2 = z*z;
    #pragma unroll
    for (int m = 32; m; m >>= 1){ s += __shfl_xor(s, m, 64); s2 += __shfl_xor(s2, m, 64); }
    float mu   = s * (1.f/64.f);
    float var  = fmaxf(s2 * (1.f/64.f) - mu*mu, 0.f);
    float rstd = rsqrtf(var + 1e-5f);
    float zn = (z - mu) * rstd * loadS(gam, lane, fm) + loadS(bet, lane, fm);
    float p0 = zn * loadS(W, lane, fm);
    float p1 = zn * loadS(W, 64 + lane, fm);
    #pragma unroll
    for (int m = 32; m; m >>= 1){ p0 += __shfl_xor(p0, m, 64); p1 += __shfl_xor(p1, m, 64); }
    if (lane == 0){
        float o0 = p0 + loadS(bias, 0, fm);
        float o1 = p1 + loadS(bias, 1, fm);
        if (fm){
            __hip_bfloat16* ob = (__hip_bfloat16*)out;
            ob[(size_t)i*2]     = __float2bfloat16(o0);
            ob[(size_t)i*2 + 1] = __float2bfloat16(o1);
        } else {
            float* of = (float*)out;
            of[(size_t)i*2]     = o0;
            of[(size_t)i*2 + 1] = o1;
        }
    }
}

// ---------------- launch ----------------
extern "C" void kernel_launch(void* const* d_in, const int* in_sizes, int n_in,
                              void* d_out, int out_size, void* d_ws, size_t ws_size,
                              hipStream_t stream)
{
    const void* x     = d_in[0];
    const int*  ei    = (const int*)d_in[1];
    const void* ea    = d_in[2];
    const void* ln1g  = d_in[3];
    const void* ln1b  = d_in[4];
    const void* fc1w  = d_in[5];
    const void* fc1b  = d_in[6];
    const void* c1rel = d_in[7];
    const void* c1bre = d_in[8];
    const void* c1roo = d_in[9];
    const void* c2rel = d_in[10];
    const void* c2bre = d_in[11];
    const void* c2roo = d_in[12];
    const void* ln2g  = d_in[13];
    const void* ln2b  = d_in[14];
    const void* fc2w  = d_in[15];
    const void* fc2b  = d_in[16];
    (void)n_in; (void)out_size; (void)ws_size;

    const int n = in_sizes[0] / N_IN_F;
    const int e = in_sizes[2];

    char* wsp = (char*)d_ws;
    size_t off = 0;
    auto alloc = [&](size_t bytes) -> char* {
        char* p = wsp + off; off += (bytes + 255) & ~(size_t)255; return p;
    };
    float* mean_  = (float*)alloc((size_t)n * 4);
    float* rstd_  = (float*)alloc((size_t)n * 4);
    int*   deg    = (int*)  alloc((size_t)n * 4);        // becomes cursor
    int*   rowoff = (int*)  alloc((size_t)(n+1) * 4);
    int*   modep  = (int*)  alloc(256);
    int*   col    = (int*)  alloc((size_t)e * 4);
    float* wgt    = (float*)alloc((size_t)e * 4);
    __hip_bfloat16* h1   = (__hip_bfloat16*)alloc((size_t)n * N_HID * 2);
    __hip_bfloat16* agg1 = (__hip_bfloat16*)alloc((size_t)n * N_HID * 2);
    __hip_bfloat16* g1   = (__hip_bfloat16*)alloc((size_t)n * N_HID * 2);
    __hip_bfloat16* agg2 = h1;    // h1 dead after conv1 GEMM
    __hip_bfloat16* g2   = agg1;  // agg1 dead after conv1 GEMM

    hipMemsetAsync(deg, 0, (size_t)n * 4, stream);
    k_detect_all<<<1, 64, 0, stream>>>(ei, (const unsigned*)x, modep);
    k_ln_stats<<<(n + 3) / 4, 256, 0, stream>>>(x, modep + 1, mean_, rstd_, n);

    k_hist    <<<(e + 255) / 256, 256, 0, stream>>>(ei, e, n, modep, deg);
    k_scan_all<<<1, 1024, 0, stream>>>(deg, n, rowoff);
    k_scatter <<<(e + 255) / 256, 256, 0, stream>>>(ei, ea, e, n, modep, deg, col, wgt);

    k_gemm1<<<(n + 63) / 64, 256, 0, stream>>>(x, modep + 1, mean_, rstd_, ln1g, ln1b, fc1w, fc1b, h1, n);

    k_agg<<<(n + 3) / 4, 256, 0, stream>>>(rowoff, col, wgt, h1, agg1, n, e);
    k_gemm_conv<128><<<(n + 63) / 64, 256, 0, stream>>>(agg1, h1, c1rel, c1roo, c1bre, modep + 1, g1, n);

    k_agg<<<(n + 3) / 4, 256, 0, stream>>>(rowoff, col, wgt, g1, agg2, n, e);
    k_gemm_conv<64><<<(n + 63) / 64, 256, 0, stream>>>(agg2, g1, c2rel, c2roo, c2bre, modep + 1, g2, n);

    k_final<<<(n + 3) / 4, 256, 0, stream>>>(g2, ln2g, ln2b, fc2w, fc2b, modep + 1, d_out, n);
}

// Round 4
// 925.072 us; speedup vs baseline: 1.4363x; 1.4363x over previous
//
#include <hip/hip_runtime.h>
#include <hip/hip_bf16.h>

#define N_IN_F 384
#define N_HID  128
#define N_OUT  64

typedef unsigned short ushort_t;
typedef __attribute__((ext_vector_type(8))) short short8v;   // 8 bf16 (4 VGPRs)
typedef __attribute__((ext_vector_type(4))) float floatx4;   // MFMA C/D

union U8 { uint4 v; unsigned short u[8]; };

__device__ __forceinline__ float bfu2f(unsigned short s){
    union { unsigned i; float f; } c; c.i = ((unsigned)s) << 16; return c.f;
}
__device__ __forceinline__ unsigned short f2bfu(float f){
    __hip_bfloat16 h = __float2bfloat16(f);
    union { __hip_bfloat16 h; unsigned short u; } c; c.h = h; return c.u;
}

// fm == 1: tensor is bf16; fm == 0: tensor is float32
__device__ __forceinline__ float loadS(const void* p, size_t i, int fm){
    return fm ? bfu2f(((const unsigned short*)p)[i]) : ((const float*)p)[i];
}

// ---------------- dtype probes ----------------
// modep[0]: 1 if edge_index is int64, 0 if int32
// modep[1]: 1 if float tensors are bf16, 0 if float32
__global__ void k_detect_all(const int* __restrict__ ei, const unsigned* __restrict__ xw,
                             int* __restrict__ modep){
    int lane = threadIdx.x & 63;
    int zi = 0;
    if (lane < 32) zi = ei[2*lane + 1];
    int cnt = 0;
    #pragma unroll
    for (int q = 0; q < 8; q++){
        unsigned w = xw[lane*8 + q];
        unsigned elo = (w >> 7) & 0xff;
        cnt += (elo >= 118 && elo <= 134) ? 1 : 0;
    }
    #pragma unroll
    for (int m = 32; m; m >>= 1){ zi |= __shfl_xor(zi, m, 64); cnt += __shfl_xor(cnt, m, 64); }
    if (lane == 0 && blockIdx.x == 0){
        modep[0] = (zi == 0) ? 1 : 0;
        modep[1] = (cnt >= 256) ? 1 : 0;
    }
}

__device__ __forceinline__ int edge_src(const int* ei, int e, int i, int mode){
    return mode ? ei[2*(size_t)i] : ei[i];
}
__device__ __forceinline__ int edge_dst(const int* ei, int e, int i, int mode){
    return mode ? ei[2*(size_t)e + 2*(size_t)i] : ei[(size_t)e + i];
}

// ---------------- LN1 row stats ----------------
__global__ __launch_bounds__(256) void k_ln_stats(
    const void* __restrict__ x, const int* __restrict__ fmp,
    float* __restrict__ mean_, float* __restrict__ rstd_, int n)
{
    int fm   = fmp[0];
    int lane = threadIdx.x & 63;
    int row  = blockIdx.x * 4 + (threadIdx.x >> 6);
    if (row >= n) return;
    float s = 0.f, s2 = 0.f;
    #pragma unroll
    for (int j = 0; j < 3; j++){
        size_t idx = (size_t)row * N_IN_F + j*128 + lane*2;
        float a, b;
        if (fm){
            unsigned u = *(const unsigned*)((const unsigned short*)x + idx);
            a = bfu2f((unsigned short)(u & 0xffff));
            b = bfu2f((unsigned short)(u >> 16));
        } else {
            float2 f = *(const float2*)((const float*)x + idx);
            a = f.x; b = f.y;
        }
        s += a + b; s2 += a*a + b*b;
    }
    #pragma unroll
    for (int m = 32; m; m >>= 1){ s += __shfl_xor(s, m, 64); s2 += __shfl_xor(s2, m, 64); }
    if (lane == 0){
        float mu  = s * (1.f/384.f);
        float var = fmaxf(s2 * (1.f/384.f) - mu*mu, 0.f);
        mean_[row] = mu;
        rstd_[row] = rsqrtf(var + 1e-5f);
    }
}

// ---------------- CSR build ----------------
__global__ void k_hist(const int* __restrict__ ei, int e, int n, const int* __restrict__ modep,
                       int* __restrict__ deg){
    int i = blockIdx.x * 256 + threadIdx.x;
    if (i >= e) return;
    int mode = modep[0];
    int d = edge_dst(ei, e, i, mode);
    if ((unsigned)d >= (unsigned)n) return;
    atomicAdd(&deg[d], 1);
}

__global__ __launch_bounds__(1024) void k_blksum(
    const int* __restrict__ deg, int n, int* __restrict__ part)
{
    __shared__ int s[1024];
    int i = blockIdx.x * 1024 + threadIdx.x;
    s[threadIdx.x] = (i < n) ? deg[i] : 0;
    __syncthreads();
    for (int off = 512; off; off >>= 1){
        if (threadIdx.x < off) s[threadIdx.x] += s[threadIdx.x + off];
        __syncthreads();
    }
    if (threadIdx.x == 0) part[blockIdx.x] = s[0];
}

__global__ void k_scanpart(int* __restrict__ part, int nb, int* __restrict__ rowoff, int n){
    if (blockIdx.x == 0 && threadIdx.x == 0){
        int run = 0;
        for (int b = 0; b < nb; b++){ int t = part[b]; part[b] = run; run += t; }
        rowoff[n] = run;
    }
}

__global__ __launch_bounds__(1024) void k_scanblk(
    int* __restrict__ deg, const int* __restrict__ part, int n, int* __restrict__ rowoff)
{
    __shared__ int s[1024];
    int t = threadIdx.x;
    int i = blockIdx.x * 1024 + t;
    int v = (i < n) ? deg[i] : 0;
    s[t] = v; __syncthreads();
    for (int off = 1; off < 1024; off <<= 1){
        int tmp = (t >= off) ? s[t - off] : 0;
        __syncthreads();
        s[t] += tmp;
        __syncthreads();
    }
    if (i < n){
        int excl = s[t] - v + part[blockIdx.x];
        rowoff[i] = excl;
        deg[i]    = excl;   // deg becomes the scatter cursor
    }
}

__global__ void k_scatter(const int* __restrict__ ei, const void* __restrict__ ea,
                          int e, int n, const int* __restrict__ modep,
                          int* __restrict__ cursor, int* __restrict__ col,
                          float* __restrict__ wgt)
{
    int i = blockIdx.x * 256 + threadIdx.x;
    if (i >= e) return;
    int mode = modep[0], fm = modep[1];
    int d = edge_dst(ei, e, i, mode);
    if ((unsigned)d >= (unsigned)n) return;
    int s = edge_src(ei, e, i, mode);
    if ((unsigned)s >= (unsigned)n) s = 0;
    int pos = atomicAdd(&cursor[d], 1);
    if ((unsigned)pos >= (unsigned)e) return;
    col[pos] = s;
    wgt[pos] = loadS(ea, i, fm);
}

// ---------------- weight prep ----------------
// Wp[j][k] = bf16(g[k]*W[j][k]);  u[j] = sum_k Wp[j][k] (as rounded);
// v[j] = sum_k b[k]*W[j][k] + fc1b[j]
__global__ __launch_bounds__(64) void k_prep_w1(
    const void* __restrict__ W, const void* __restrict__ g, const void* __restrict__ b,
    const void* __restrict__ fc1b, const int* __restrict__ fmp,
    ushort_t* __restrict__ Wp, float* __restrict__ u, float* __restrict__ v)
{
    int fm = fmp[0];
    int j = blockIdx.x, lane = threadIdx.x;
    float su = 0.f, sv = 0.f;
    for (int k = lane; k < N_IN_F; k += 64){
        float w  = loadS(W, (size_t)j*N_IN_F + k, fm);
        float gk = loadS(g, k, fm);
        float bk = loadS(b, k, fm);
        unsigned short pw = f2bfu(gk * w);
        Wp[(size_t)j*N_IN_F + k] = pw;
        su += bfu2f(pw);
        sv += bk * w;
    }
    #pragma unroll
    for (int m = 32; m; m >>= 1){ su += __shfl_xor(su, m, 64); sv += __shfl_xor(sv, m, 64); }
    if (lane == 0){
        u[j] = su;
        v[j] = sv + loadS(fc1b, j, fm);
    }
}

// convert the 4 conv weight tensors to bf16: [c1rel 16384][c1roo 16384][c2rel 8192][c2roo 8192]
__global__ void k_cvt4(const void* __restrict__ p0, const void* __restrict__ p1,
                       const void* __restrict__ p2, const void* __restrict__ p3,
                       const int* __restrict__ fmp, ushort_t* __restrict__ o)
{
    int fm = fmp[0];
    int i = blockIdx.x * 256 + threadIdx.x;
    if (i >= 49152) return;
    const void* p; int off;
    if (i < 16384)      { p = p0; off = i; }
    else if (i < 32768) { p = p1; off = i - 16384; }
    else if (i < 40960) { p = p2; off = i - 32768; }
    else                { p = p3; off = i - 40960; }
    o[i] = f2bfu(loadS(p, off, fm));
}

// ---------------- MFMA GEMM1: h1 = rs*(x @ Wp^T) - rs*m*u + v ----------------
// block: 4 waves (2x2), 128 rows x 128 cols; wave: 64x64 (4x4 tiles of 16x16x32)
__global__ __launch_bounds__(256) void k_gemm1_mfma(
    const void* __restrict__ x, const int* __restrict__ fmp,
    const float* __restrict__ mean_, const float* __restrict__ rstd_,
    const ushort_t* __restrict__ Wp,
    const float* __restrict__ u, const float* __restrict__ v,
    ushort_t* __restrict__ out, int n)
{
    int fm = fmp[0];
    int t = threadIdx.x;
    int wave = t >> 6, lane = t & 63;
    int r16 = lane & 15, kq = lane >> 4;
    int wy = wave >> 1, wx = wave & 1;
    int m0 = blockIdx.x * 128 + wy * 64;
    int n0 = wx * 64;

    int rA[4];
    #pragma unroll
    for (int mi = 0; mi < 4; mi++) rA[mi] = min(m0 + mi*16 + r16, n - 1);

    floatx4 acc[4][4];
    #pragma unroll
    for (int a = 0; a < 4; a++)
        #pragma unroll
        for (int c = 0; c < 4; c++)
            acc[a][c] = (floatx4){0.f, 0.f, 0.f, 0.f};

    for (int ks = 0; ks < N_IN_F/32; ks++){
        int kb = ks*32 + kq*8;
        short8v af[4], bfr[4];
        #pragma unroll
        for (int mi = 0; mi < 4; mi++){
            size_t idx = (size_t)rA[mi]*N_IN_F + kb;
            if (fm){
                af[mi] = *(const short8v*)((const ushort_t*)x + idx);
            } else {
                const float* xf = (const float*)x + idx;
                floatx4 p = *(const floatx4*)xf;
                floatx4 q = *(const floatx4*)(xf + 4);
                short8v r;
                r[0]=(short)f2bfu(p[0]); r[1]=(short)f2bfu(p[1]);
                r[2]=(short)f2bfu(p[2]); r[3]=(short)f2bfu(p[3]);
                r[4]=(short)f2bfu(q[0]); r[5]=(short)f2bfu(q[1]);
                r[6]=(short)f2bfu(q[2]); r[7]=(short)f2bfu(q[3]);
                af[mi] = r;
            }
        }
        #pragma unroll
        for (int ni = 0; ni < 4; ni++)
            bfr[ni] = *(const short8v*)(Wp + (size_t)(n0 + ni*16 + r16)*N_IN_F + kb);
        #pragma unroll
        for (int mi = 0; mi < 4; mi++)
            #pragma unroll
            for (int ni = 0; ni < 4; ni++)
                acc[mi][ni] = __builtin_amdgcn_mfma_f32_16x16x32_bf16(
                    af[mi], bfr[ni], acc[mi][ni], 0, 0, 0);
    }

    // epilogue: C/D layout col=lane&15, row=kq*4+r
    #pragma unroll
    for (int mi = 0; mi < 4; mi++){
        int ib = m0 + mi*16 + kq*4;
        float mm[4], rr[4];
        #pragma unroll
        for (int r = 0; r < 4; r++){
            int ii = min(ib + r, n - 1);
            mm[r] = mean_[ii]; rr[r] = rstd_[ii];
        }
        #pragma unroll
        for (int ni = 0; ni < 4; ni++){
            int j = n0 + ni*16 + r16;
            float uj = u[j], vj = v[j];
            #pragma unroll
            for (int r = 0; r < 4; r++){
                int ii = ib + r;
                float val = rr[r]*acc[mi][ni][r] - rr[r]*mm[r]*uj + vj;
                if (ii < n) out[(size_t)ii*N_HID + j] = f2bfu(val);
            }
        }
    }
}

// ---------------- MFMA conv GEMM: leaky(A1@W1^T + A2@W2^T + bias) ----------------
// WX=2: block 128 rows x 128 cols (waves 2x2). WX=1: block 256 rows x 64 cols (waves 4x1).
template<int WX>
__global__ __launch_bounds__(256) void k_conv_mfma(
    const ushort_t* __restrict__ A1, const ushort_t* __restrict__ A2,
    const ushort_t* __restrict__ W1, const ushort_t* __restrict__ W2,
    const void* __restrict__ bias, const int* __restrict__ fmp,
    ushort_t* __restrict__ out, int n)
{
    constexpr int WY = 4 / WX;
    constexpr int BN = WX * 64;
    int fm = fmp[0];
    int t = threadIdx.x;
    int wave = t >> 6, lane = t & 63;
    int r16 = lane & 15, kq = lane >> 4;
    int wy = wave / WX, wx = wave % WX;
    int m0 = blockIdx.x * (WY*64) + wy * 64;
    int n0 = wx * 64;

    int rA[4];
    #pragma unroll
    for (int mi = 0; mi < 4; mi++) rA[mi] = min(m0 + mi*16 + r16, n - 1);

    floatx4 acc[4][4];
    #pragma unroll
    for (int a = 0; a < 4; a++)
        #pragma unroll
        for (int c = 0; c < 4; c++)
            acc[a][c] = (floatx4){0.f, 0.f, 0.f, 0.f};

    #pragma unroll
    for (int p = 0; p < 2; p++){
        const ushort_t* A = p ? A2 : A1;
        const ushort_t* W = p ? W2 : W1;
        #pragma unroll
        for (int ks = 0; ks < 4; ks++){
            int kb = ks*32 + kq*8;
            short8v af[4], bfr[4];
            #pragma unroll
            for (int mi = 0; mi < 4; mi++)
                af[mi] = *(const short8v*)(A + (size_t)rA[mi]*N_HID + kb);
            #pragma unroll
            for (int ni = 0; ni < 4; ni++)
                bfr[ni] = *(const short8v*)(W + (size_t)(n0 + ni*16 + r16)*N_HID + kb);
            #pragma unroll
            for (int mi = 0; mi < 4; mi++)
                #pragma unroll
                for (int ni = 0; ni < 4; ni++)
                    acc[mi][ni] = __builtin_amdgcn_mfma_f32_16x16x32_bf16(
                        af[mi], bfr[ni], acc[mi][ni], 0, 0, 0);
        }
    }

    #pragma unroll
    for (int ni = 0; ni < 4; ni++){
        int j = n0 + ni*16 + r16;
        float bb = loadS(bias, j, fm);
        #pragma unroll
        for (int mi = 0; mi < 4; mi++){
            int ib = m0 + mi*16 + kq*4;
            #pragma unroll
            for (int r = 0; r < 4; r++){
                int ii = ib + r;
                float val = acc[mi][ni][r] + bb;
                val = (val >= 0.f) ? val : 0.01f * val;
                if (ii < n) out[(size_t)ii*BN + j] = f2bfu(val);
            }
        }
    }
}

// ---------------- CSR aggregation ----------------
__global__ __launch_bounds__(256) void k_agg(
    const int* __restrict__ rowoff, const int* __restrict__ col,
    const float* __restrict__ wgt,
    const ushort_t* __restrict__ src_mat,   // [n,128] bf16
    ushort_t* __restrict__ out, int n, int eTot)
{
    int lane = threadIdx.x & 63;
    int d    = blockIdx.x * 4 + (threadIdx.x >> 6);
    if (d >= n) return;
    int e0 = rowoff[d], e1 = rowoff[d+1];
    e0 = max(0, min(e0, eTot));
    e1 = max(e0, min(e1, eTot));
    float ax = 0.f, ay = 0.f;
    for (int e = e0; e < e1; e++){
        int s = col[e];
        if ((unsigned)s >= (unsigned)n) s = 0;
        float wv = wgt[e];
        unsigned u = *(const unsigned*)(src_mat + (size_t)s*N_HID + lane*2);
        ax += wv * bfu2f((unsigned short)(u & 0xffff));
        ay += wv * bfu2f((unsigned short)(u >> 16));
    }
    unsigned pk = ((unsigned)f2bfu(ay) << 16) | (unsigned)f2bfu(ax);
    *(unsigned*)(out + (size_t)d*N_HID + lane*2) = pk;
}

// ---------------- final: LN2 + fc2 (64 -> 2) ----------------
__global__ __launch_bounds__(256) void k_final(
    const ushort_t* __restrict__ g2,   // [n,64] bf16
    const void* __restrict__ gam, const void* __restrict__ bet,
    const void* __restrict__ W, const void* __restrict__ bias,
    const int* __restrict__ fmp,
    void* __restrict__ out, int n)
{
    int fm   = fmp[0];
    int lane = threadIdx.x & 63;
    int i    = blockIdx.x * 4 + (threadIdx.x >> 6);
    if (i >= n) return;
    float z = bfu2f(g2[(size_t)i*64 + lane]);
    float s = z, s2 = z*z;
    #pragma unroll
    for (int m = 32; m; m >>= 1){ s += __shfl_xor(s, m, 64); s2 += __shfl_xor(s2, m, 64); }
    float mu   = s * (1.f/64.f);
    float var  = fmaxf(s2 * (1.f/64.f) - mu*mu, 0.f);
    float rstd = rsqrtf(var + 1e-5f);
    float zn = (z - mu) * rstd * loadS(gam, lane, fm) + loadS(bet, lane, fm);
    float p0 = zn * loadS(W, lane, fm);
    float p1 = zn * loadS(W, 64 + lane, fm);
    #pragma unroll
    for (int m = 32; m; m >>= 1){ p0 += __shfl_xor(p0, m, 64); p1 += __shfl_xor(p1, m, 64); }
    if (lane == 0){
        float o0 = p0 + loadS(bias, 0, fm);
        float o1 = p1 + loadS(bias, 1, fm);
        if (fm){
            ushort_t* ob = (ushort_t*)out;
            ob[(size_t)i*2]     = f2bfu(o0);
            ob[(size_t)i*2 + 1] = f2bfu(o1);
        } else {
            float* of = (float*)out;
            of[(size_t)i*2]     = o0;
            of[(size_t)i*2 + 1] = o1;
        }
    }
}

// ---------------- launch ----------------
extern "C" void kernel_launch(void* const* d_in, const int* in_sizes, int n_in,
                              void* d_out, int out_size, void* d_ws, size_t ws_size,
                              hipStream_t stream)
{
    const void* x     = d_in[0];
    const int*  ei    = (const int*)d_in[1];
    const void* ea    = d_in[2];
    const void* ln1g  = d_in[3];
    const void* ln1b  = d_in[4];
    const void* fc1w  = d_in[5];
    const void* fc1b  = d_in[6];
    const void* c1rel = d_in[7];
    const void* c1bre = d_in[8];
    const void* c1roo = d_in[9];
    const void* c2rel = d_in[10];
    const void* c2bre = d_in[11];
    const void* c2roo = d_in[12];
    const void* ln2g  = d_in[13];
    const void* ln2b  = d_in[14];
    const void* fc2w  = d_in[15];
    const void* fc2b  = d_in[16];
    (void)n_in; (void)out_size; (void)ws_size;

    const int n = in_sizes[0] / N_IN_F;
    const int e = in_sizes[2];

    char* wsp = (char*)d_ws;
    size_t off = 0;
    auto alloc = [&](size_t bytes) -> char* {
        char* p = wsp + off; off += (bytes + 255) & ~(size_t)255; return p;
    };
    float*    mean_  = (float*)alloc((size_t)n * 4);
    float*    rstd_  = (float*)alloc((size_t)n * 4);
    int*      deg    = (int*)  alloc((size_t)n * 4);        // becomes cursor
    int*      rowoff = (int*)  alloc((size_t)(n+1) * 4);
    int*      part   = (int*)  alloc(4096);
    int*      modep  = (int*)  alloc(256);
    int*      col    = (int*)  alloc((size_t)e * 4);
    float*    wgt    = (float*)alloc((size_t)e * 4);
    float*    u      = (float*)alloc(128 * 4);
    float*    v      = (float*)alloc(128 * 4);
    ushort_t* Wp     = (ushort_t*)alloc((size_t)N_HID * N_IN_F * 2);
    ushort_t* cw     = (ushort_t*)alloc((size_t)49152 * 2);
    ushort_t* h1     = (ushort_t*)alloc((size_t)n * N_HID * 2);
    ushort_t* agg1   = (ushort_t*)alloc((size_t)n * N_HID * 2);
    ushort_t* g1     = (ushort_t*)alloc((size_t)n * N_HID * 2);
    ushort_t* agg2   = h1;    // h1 dead after conv1 GEMM
    ushort_t* g2     = agg1;  // agg1 dead after conv1 GEMM

    hipMemsetAsync(deg, 0, (size_t)n * 4, stream);
    k_detect_all<<<1, 64, 0, stream>>>(ei, (const unsigned*)x, modep);
    k_ln_stats<<<(n + 3) / 4, 256, 0, stream>>>(x, modep + 1, mean_, rstd_, n);

    int nb = (n + 1023) / 1024;
    k_hist    <<<(e + 255) / 256, 256, 0, stream>>>(ei, e, n, modep, deg);
    k_blksum  <<<nb, 1024, 0, stream>>>(deg, n, part);
    k_scanpart<<<1, 64, 0, stream>>>(part, nb, rowoff, n);
    k_scanblk <<<nb, 1024, 0, stream>>>(deg, part, n, rowoff);
    k_scatter <<<(e + 255) / 256, 256, 0, stream>>>(ei, ea, e, n, modep, deg, col, wgt);

    k_prep_w1<<<N_HID, 64, 0, stream>>>(fc1w, ln1g, ln1b, fc1b, modep + 1, Wp, u, v);
    k_cvt4   <<<(49152 + 255) / 256, 256, 0, stream>>>(c1rel, c1roo, c2rel, c2roo, modep + 1, cw);

    k_gemm1_mfma<<<(n + 127) / 128, 256, 0, stream>>>(x, modep + 1, mean_, rstd_, Wp, u, v, h1, n);

    k_agg<<<(n + 3) / 4, 256, 0, stream>>>(rowoff, col, wgt, h1, agg1, n, e);
    k_conv_mfma<2><<<(n + 127) / 128, 256, 0, stream>>>(agg1, h1, cw, cw + 16384, c1bre, modep + 1, g1, n);

    k_agg<<<(n + 3) / 4, 256, 0, stream>>>(rowoff, col, wgt, g1, agg2, n, e);
    k_conv_mfma<1><<<(n + 255) / 256, 256, 0, stream>>>(agg2, g1, cw + 32768, cw + 40960, c2bre, modep + 1, g2, n);

    k_final<<<(n + 3) / 4, 256, 0, stream>>>(g2, ln2g, ln2b, fc2w, fc2b, modep + 1, d_out, n);
}

// Round 5
// 728.275 us; speedup vs baseline: 1.8244x; 1.2702x over previous
//
#include <hip/hip_runtime.h>
#include <hip/hip_bf16.h>

#define N_IN_F 384
#define N_HID  128
#define N_OUT  64

typedef unsigned short ushort_t;
typedef __attribute__((ext_vector_type(8))) short short8v;   // 8 bf16 (4 VGPRs)
typedef __attribute__((ext_vector_type(4))) float floatx4;   // MFMA C/D

union U8 { uint4 v; unsigned short u[8]; };

__device__ __forceinline__ float bfu2f(unsigned short s){
    union { unsigned i; float f; } c; c.i = ((unsigned)s) << 16; return c.f;
}
__device__ __forceinline__ unsigned short f2bfu(float f){
    __hip_bfloat16 h = __float2bfloat16(f);
    union { __hip_bfloat16 h; unsigned short u; } c; c.h = h; return c.u;
}

// fm == 1: tensor is bf16; fm == 0: tensor is float32
__device__ __forceinline__ float loadS(const void* p, size_t i, int fm){
    return fm ? bfu2f(((const unsigned short*)p)[i]) : ((const float*)p)[i];
}

// ---------------- dtype probes ----------------
__global__ void k_detect_all(const int* __restrict__ ei, const unsigned* __restrict__ xw,
                             int* __restrict__ modep){
    int lane = threadIdx.x & 63;
    int zi = 0;
    if (lane < 32) zi = ei[2*lane + 1];
    int cnt = 0;
    #pragma unroll
    for (int q = 0; q < 8; q++){
        unsigned w = xw[lane*8 + q];
        unsigned elo = (w >> 7) & 0xff;
        cnt += (elo >= 118 && elo <= 134) ? 1 : 0;
    }
    #pragma unroll
    for (int m = 32; m; m >>= 1){ zi |= __shfl_xor(zi, m, 64); cnt += __shfl_xor(cnt, m, 64); }
    if (lane == 0 && blockIdx.x == 0){
        modep[0] = (zi == 0) ? 1 : 0;
        modep[1] = (cnt >= 256) ? 1 : 0;
    }
}

__device__ __forceinline__ int edge_src(const int* ei, int e, int i, int mode){
    return mode ? ei[2*(size_t)i] : ei[i];
}
__device__ __forceinline__ int edge_dst(const int* ei, int e, int i, int mode){
    return mode ? ei[2*(size_t)e + 2*(size_t)i] : ei[(size_t)e + i];
}

// ---------------- CSR build ----------------
__global__ void k_hist(const int* __restrict__ ei, int e, int n, const int* __restrict__ modep,
                       int* __restrict__ deg){
    int i = blockIdx.x * 256 + threadIdx.x;
    if (i >= e) return;
    int mode = modep[0];
    int d = edge_dst(ei, e, i, mode);
    if ((unsigned)d >= (unsigned)n) return;
    atomicAdd(&deg[d], 1);
}

__global__ __launch_bounds__(1024) void k_blksum(
    const int* __restrict__ deg, int n, int* __restrict__ part)
{
    __shared__ int s[1024];
    int i = blockIdx.x * 1024 + threadIdx.x;
    s[threadIdx.x] = (i < n) ? deg[i] : 0;
    __syncthreads();
    for (int off = 512; off; off >>= 1){
        if (threadIdx.x < off) s[threadIdx.x] += s[threadIdx.x + off];
        __syncthreads();
    }
    if (threadIdx.x == 0) part[blockIdx.x] = s[0];
}

// parallel scan of nb (<=128) partials; part becomes exclusive, rowoff[n]=total
__global__ __launch_bounds__(128) void k_scanpart(
    int* __restrict__ part, int nb, int* __restrict__ rowoff, int n)
{
    __shared__ int s[128];
    int t = threadIdx.x;
    if (nb <= 128){
        int v = (t < nb) ? part[t] : 0;
        s[t] = v; __syncthreads();
        #pragma unroll
        for (int off = 1; off < 128; off <<= 1){
            int tmp = (t >= off) ? s[t - off] : 0;
            __syncthreads();
            s[t] += tmp;
            __syncthreads();
        }
        if (t < nb) part[t] = s[t] - v;
        if (t == 127) rowoff[n] = s[127];
    } else if (t == 0){
        int run = 0;
        for (int b = 0; b < nb; b++){ int tt = part[b]; part[b] = run; run += tt; }
        rowoff[n] = run;
    }
}

__global__ __launch_bounds__(1024) void k_scanblk(
    int* __restrict__ deg, const int* __restrict__ part, int n, int* __restrict__ rowoff)
{
    __shared__ int s[1024];
    int t = threadIdx.x;
    int i = blockIdx.x * 1024 + t;
    int v = (i < n) ? deg[i] : 0;
    s[t] = v; __syncthreads();
    for (int off = 1; off < 1024; off <<= 1){
        int tmp = (t >= off) ? s[t - off] : 0;
        __syncthreads();
        s[t] += tmp;
        __syncthreads();
    }
    if (i < n){
        int excl = s[t] - v + part[blockIdx.x];
        rowoff[i] = excl;
        deg[i]    = excl;   // deg becomes the scatter cursor
    }
}

__global__ void k_scatter(const int* __restrict__ ei, const void* __restrict__ ea,
                          int e, int n, const int* __restrict__ modep,
                          int* __restrict__ cursor, int* __restrict__ col,
                          float* __restrict__ wgt)
{
    int i = blockIdx.x * 256 + threadIdx.x;
    if (i >= e) return;
    int mode = modep[0], fm = modep[1];
    int d = edge_dst(ei, e, i, mode);
    if ((unsigned)d >= (unsigned)n) return;
    int s = edge_src(ei, e, i, mode);
    if ((unsigned)s >= (unsigned)n) s = 0;
    int pos = atomicAdd(&cursor[d], 1);
    if ((unsigned)pos >= (unsigned)e) return;
    col[pos] = s;
    wgt[pos] = loadS(ea, i, fm);
}

// ---------------- weight prep ----------------
__global__ __launch_bounds__(64) void k_prep_w1(
    const void* __restrict__ W, const void* __restrict__ g, const void* __restrict__ b,
    const void* __restrict__ fc1b, const int* __restrict__ fmp,
    ushort_t* __restrict__ Wp, float* __restrict__ u, float* __restrict__ v)
{
    int fm = fmp[0];
    int j = blockIdx.x, lane = threadIdx.x;
    float su = 0.f, sv = 0.f;
    for (int k = lane; k < N_IN_F; k += 64){
        float w  = loadS(W, (size_t)j*N_IN_F + k, fm);
        float gk = loadS(g, k, fm);
        float bk = loadS(b, k, fm);
        unsigned short pw = f2bfu(gk * w);
        Wp[(size_t)j*N_IN_F + k] = pw;
        su += bfu2f(pw);
        sv += bk * w;
    }
    #pragma unroll
    for (int m = 32; m; m >>= 1){ su += __shfl_xor(su, m, 64); sv += __shfl_xor(sv, m, 64); }
    if (lane == 0){
        u[j] = su;
        v[j] = sv + loadS(fc1b, j, fm);
    }
}

__global__ void k_cvt4(const void* __restrict__ p0, const void* __restrict__ p1,
                       const void* __restrict__ p2, const void* __restrict__ p3,
                       const int* __restrict__ fmp, ushort_t* __restrict__ o)
{
    int fm = fmp[0];
    int i = blockIdx.x * 256 + threadIdx.x;
    if (i >= 49152) return;
    const void* p; int off;
    if (i < 16384)      { p = p0; off = i; }
    else if (i < 32768) { p = p1; off = i - 16384; }
    else if (i < 40960) { p = p2; off = i - 32768; }
    else                { p = p3; off = i - 40960; }
    o[i] = f2bfu(loadS(p, off, fm));
}

// ---------------- MFMA GEMM1 with fused LN stats ----------------
// block: 4 waves stacked (128 rows), each wave 32 rows x 128 cols.
// h1 = rs*(x @ Wp^T) - rs*m*u + v   (stats computed in-kernel)
__global__ __launch_bounds__(256) void k_gemm1_mfma(
    const void* __restrict__ x, const int* __restrict__ fmp,
    const ushort_t* __restrict__ Wp,
    const float* __restrict__ u, const float* __restrict__ v,
    ushort_t* __restrict__ out, int n)
{
    int fm = fmp[0];
    int t = threadIdx.x;
    int wave = t >> 6, lane = t & 63;
    int r16 = lane & 15, kq = lane >> 4;
    int m0 = blockIdx.x * 128 + wave * 32;

    int rA[2];
    rA[0] = min(m0 + r16,      n - 1);
    rA[1] = min(m0 + 16 + r16, n - 1);

    floatx4 acc[2][8];
    #pragma unroll
    for (int a = 0; a < 2; a++)
        #pragma unroll
        for (int c = 0; c < 8; c++)
            acc[a][c] = (floatx4){0.f, 0.f, 0.f, 0.f};

    float s1[2] = {0.f, 0.f}, s2[2] = {0.f, 0.f};

    for (int ks = 0; ks < N_IN_F/32; ks++){
        int kb = ks*32 + kq*8;
        short8v af[2];
        #pragma unroll
        for (int mi = 0; mi < 2; mi++){
            size_t idx = (size_t)rA[mi]*N_IN_F + kb;
            float f[8];
            if (fm){
                short8v sv = *(const short8v*)((const ushort_t*)x + idx);
                af[mi] = sv;
                #pragma unroll
                for (int q = 0; q < 8; q++) f[q] = bfu2f((unsigned short)sv[q]);
            } else {
                const float* xf = (const float*)x + idx;
                floatx4 p = *(const floatx4*)xf;
                floatx4 q4 = *(const floatx4*)(xf + 4);
                f[0]=p[0]; f[1]=p[1]; f[2]=p[2]; f[3]=p[3];
                f[4]=q4[0]; f[5]=q4[1]; f[6]=q4[2]; f[7]=q4[3];
                short8v r;
                #pragma unroll
                for (int q = 0; q < 8; q++) r[q] = (short)f2bfu(f[q]);
                af[mi] = r;
            }
            #pragma unroll
            for (int q = 0; q < 8; q++){ s1[mi] += f[q]; s2[mi] += f[q]*f[q]; }
        }
        short8v bfr[8];
        #pragma unroll
        for (int ni = 0; ni < 8; ni++)
            bfr[ni] = *(const short8v*)(Wp + (size_t)(ni*16 + r16)*N_IN_F + kb);
        #pragma unroll
        for (int mi = 0; mi < 2; mi++)
            #pragma unroll
            for (int ni = 0; ni < 8; ni++)
                acc[mi][ni] = __builtin_amdgcn_mfma_f32_16x16x32_bf16(
                    af[mi], bfr[ni], acc[mi][ni], 0, 0, 0);
    }

    // finish stats: reduce across the 4 kq-lanes holding the same row
    float mu[2], rs[2];
    #pragma unroll
    for (int mi = 0; mi < 2; mi++){
        s1[mi] += __shfl_xor(s1[mi], 16, 64); s1[mi] += __shfl_xor(s1[mi], 32, 64);
        s2[mi] += __shfl_xor(s2[mi], 16, 64); s2[mi] += __shfl_xor(s2[mi], 32, 64);
        mu[mi] = s1[mi] * (1.f/384.f);
        float var = fmaxf(s2[mi] * (1.f/384.f) - mu[mi]*mu[mi], 0.f);
        rs[mi] = rsqrtf(var + 1e-5f);
    }

    // epilogue: C/D layout col=lane&15, row=kq*4+r
    #pragma unroll
    for (int mi = 0; mi < 2; mi++){
        int ib = m0 + mi*16 + kq*4;
        float mm[4], rr[4];
        #pragma unroll
        for (int r = 0; r < 4; r++){
            mm[r] = __shfl(mu[mi], kq*4 + r, 64);
            rr[r] = __shfl(rs[mi], kq*4 + r, 64);
        }
        #pragma unroll
        for (int ni = 0; ni < 8; ni++){
            int j = ni*16 + r16;
            float uj = u[j], vj = v[j];
            #pragma unroll
            for (int r = 0; r < 4; r++){
                int ii = ib + r;
                float val = rr[r]*acc[mi][ni][r] - rr[r]*mm[r]*uj + vj;
                if (ii < n) out[(size_t)ii*N_HID + j] = f2bfu(val);
            }
        }
    }
}

// ---------------- MFMA conv GEMM: leaky(A1@W1^T + A2@W2^T + bias) ----------------
// block: 4 waves stacked (128 rows), each wave 32 rows x BN cols.
template<int BN>
__global__ __launch_bounds__(256) void k_conv_mfma(
    const ushort_t* __restrict__ A1, const ushort_t* __restrict__ A2,
    const ushort_t* __restrict__ W1, const ushort_t* __restrict__ W2,
    const void* __restrict__ bias, const int* __restrict__ fmp,
    ushort_t* __restrict__ out, int n)
{
    constexpr int NT = BN / 16;
    int fm = fmp[0];
    int t = threadIdx.x;
    int wave = t >> 6, lane = t & 63;
    int r16 = lane & 15, kq = lane >> 4;
    int m0 = blockIdx.x * 128 + wave * 32;

    int rA[2];
    rA[0] = min(m0 + r16,      n - 1);
    rA[1] = min(m0 + 16 + r16, n - 1);

    floatx4 acc[2][NT];
    #pragma unroll
    for (int a = 0; a < 2; a++)
        #pragma unroll
        for (int c = 0; c < NT; c++)
            acc[a][c] = (floatx4){0.f, 0.f, 0.f, 0.f};

    #pragma unroll
    for (int p = 0; p < 2; p++){
        const ushort_t* A = p ? A2 : A1;
        const ushort_t* W = p ? W2 : W1;
        #pragma unroll
        for (int ks = 0; ks < 4; ks++){
            int kb = ks*32 + kq*8;
            short8v af[2], bfr[NT];
            #pragma unroll
            for (int mi = 0; mi < 2; mi++)
                af[mi] = *(const short8v*)(A + (size_t)rA[mi]*N_HID + kb);
            #pragma unroll
            for (int ni = 0; ni < NT; ni++)
                bfr[ni] = *(const short8v*)(W + (size_t)(ni*16 + r16)*N_HID + kb);
            #pragma unroll
            for (int mi = 0; mi < 2; mi++)
                #pragma unroll
                for (int ni = 0; ni < NT; ni++)
                    acc[mi][ni] = __builtin_amdgcn_mfma_f32_16x16x32_bf16(
                        af[mi], bfr[ni], acc[mi][ni], 0, 0, 0);
        }
    }

    #pragma unroll
    for (int ni = 0; ni < NT; ni++){
        int j = ni*16 + r16;
        float bb = loadS(bias, j, fm);
        #pragma unroll
        for (int mi = 0; mi < 2; mi++){
            int ib = m0 + mi*16 + kq*4;
            #pragma unroll
            for (int r = 0; r < 4; r++){
                int ii = ib + r;
                float val = acc[mi][ni][r] + bb;
                val = (val >= 0.f) ? val : 0.01f * val;
                if (ii < n) out[(size_t)ii*BN + j] = f2bfu(val);
            }
        }
    }
}

// ---------------- CSR aggregation: 4-edge MLP, 16B row loads ----------------
__global__ __launch_bounds__(256) void k_agg(
    const int* __restrict__ rowoff, const int* __restrict__ col,
    const float* __restrict__ wgt,
    const ushort_t* __restrict__ src_mat,   // [n,128] bf16
    ushort_t* __restrict__ out, int n, int eTot)
{
    int t = threadIdx.x;
    int lane = t & 63;
    int d = blockIdx.x * 4 + (t >> 6);
    if (d >= n) return;
    int grp = lane >> 4;     // 0..3: edge interleave
    int c16 = lane & 15;     // 16B column segment (8 bf16)
    int e0 = rowoff[d], e1 = rowoff[d+1];
    e0 = max(0, min(e0, eTot));
    e1 = max(e0, min(e1, eTot));
    float acc[8] = {};
    for (int e = e0 + grp; e < e1; e += 4){
        int s = col[e];
        if ((unsigned)s >= (unsigned)n) s = 0;
        float wv = wgt[e];
        U8 u; u.v = *(const uint4*)(src_mat + (size_t)s*N_HID + c16*8);
        #pragma unroll
        for (int q = 0; q < 8; q++) acc[q] += wv * bfu2f(u.u[q]);
    }
    // reduce the 4 edge-groups (same c16 live at lane ^16, ^32)
    #pragma unroll
    for (int q = 0; q < 8; q++){
        acc[q] += __shfl_xor(acc[q], 16, 64);
        acc[q] += __shfl_xor(acc[q], 32, 64);
    }
    if (grp == 0){
        union { ushort_t u[8]; uint4 v; } P;
        #pragma unroll
        for (int q = 0; q < 8; q++) P.u[q] = f2bfu(acc[q]);
        *(uint4*)(out + (size_t)d*N_HID + c16*8) = P.v;
    }
}

// ---------------- final: LN2 + fc2 (64 -> 2) ----------------
__global__ __launch_bounds__(256) void k_final(
    const ushort_t* __restrict__ g2,   // [n,64] bf16
    const void* __restrict__ gam, const void* __restrict__ bet,
    const void* __restrict__ W, const void* __restrict__ bias,
    const int* __restrict__ fmp,
    void* __restrict__ out, int n)
{
    int fm   = fmp[0];
    int lane = threadIdx.x & 63;
    int i    = blockIdx.x * 4 + (threadIdx.x >> 6);
    if (i >= n) return;
    float z = bfu2f(g2[(size_t)i*64 + lane]);
    float s = z, s2 = z*z;
    #pragma unroll
    for (int m = 32; m; m >>= 1){ s += __shfl_xor(s, m, 64); s2 += __shfl_xor(s2, m, 64); }
    float mu   = s * (1.f/64.f);
    float var  = fmaxf(s2 * (1.f/64.f) - mu*mu, 0.f);
    float rstd = rsqrtf(var + 1e-5f);
    float zn = (z - mu) * rstd * loadS(gam, lane, fm) + loadS(bet, lane, fm);
    float p0 = zn * loadS(W, lane, fm);
    float p1 = zn * loadS(W, 64 + lane, fm);
    #pragma unroll
    for (int m = 32; m; m >>= 1){ p0 += __shfl_xor(p0, m, 64); p1 += __shfl_xor(p1, m, 64); }
    if (lane == 0){
        float o0 = p0 + loadS(bias, 0, fm);
        float o1 = p1 + loadS(bias, 1, fm);
        if (fm){
            ushort_t* ob = (ushort_t*)out;
            ob[(size_t)i*2]     = f2bfu(o0);
            ob[(size_t)i*2 + 1] = f2bfu(o1);
        } else {
            float* of = (float*)out;
            of[(size_t)i*2]     = o0;
            of[(size_t)i*2 + 1] = o1;
        }
    }
}

// ---------------- launch ----------------
extern "C" void kernel_launch(void* const* d_in, const int* in_sizes, int n_in,
                              void* d_out, int out_size, void* d_ws, size_t ws_size,
                              hipStream_t stream)
{
    const void* x     = d_in[0];
    const int*  ei    = (const int*)d_in[1];
    const void* ea    = d_in[2];
    const void* ln1g  = d_in[3];
    const void* ln1b  = d_in[4];
    const void* fc1w  = d_in[5];
    const void* fc1b  = d_in[6];
    const void* c1rel = d_in[7];
    const void* c1bre = d_in[8];
    const void* c1roo = d_in[9];
    const void* c2rel = d_in[10];
    const void* c2bre = d_in[11];
    const void* c2roo = d_in[12];
    const void* ln2g  = d_in[13];
    const void* ln2b  = d_in[14];
    const void* fc2w  = d_in[15];
    const void* fc2b  = d_in[16];
    (void)n_in; (void)out_size; (void)ws_size;

    const int n = in_sizes[0] / N_IN_F;
    const int e = in_sizes[2];

    char* wsp = (char*)d_ws;
    size_t off = 0;
    auto alloc = [&](size_t bytes) -> char* {
        char* p = wsp + off; off += (bytes + 255) & ~(size_t)255; return p;
    };
    int*      deg    = (int*)  alloc((size_t)n * 4);        // becomes cursor
    int*      rowoff = (int*)  alloc((size_t)(n+1) * 4);
    int*      part   = (int*)  alloc(4096);
    int*      modep  = (int*)  alloc(256);
    int*      col    = (int*)  alloc((size_t)e * 4);
    float*    wgt    = (float*)alloc((size_t)e * 4);
    float*    u      = (float*)alloc(128 * 4);
    float*    v      = (float*)alloc(128 * 4);
    ushort_t* Wp     = (ushort_t*)alloc((size_t)N_HID * N_IN_F * 2);
    ushort_t* cw     = (ushort_t*)alloc((size_t)49152 * 2);
    ushort_t* h1     = (ushort_t*)alloc((size_t)n * N_HID * 2);
    ushort_t* agg1   = (ushort_t*)alloc((size_t)n * N_HID * 2);
    ushort_t* g1     = (ushort_t*)alloc((size_t)n * N_HID * 2);
    ushort_t* agg2   = h1;    // h1 dead after conv1 GEMM
    ushort_t* g2     = agg1;  // agg1 dead after conv1 GEMM

    hipMemsetAsync(deg, 0, (size_t)n * 4, stream);
    k_detect_all<<<1, 64, 0, stream>>>(ei, (const unsigned*)x, modep);

    int nb = (n + 1023) / 1024;
    k_hist    <<<(e + 255) / 256, 256, 0, stream>>>(ei, e, n, modep, deg);
    k_blksum  <<<nb, 1024, 0, stream>>>(deg, n, part);
    k_scanpart<<<1, 128, 0, stream>>>(part, nb, rowoff, n);
    k_scanblk <<<nb, 1024, 0, stream>>>(deg, part, n, rowoff);
    k_scatter <<<(e + 255) / 256, 256, 0, stream>>>(ei, ea, e, n, modep, deg, col, wgt);

    k_prep_w1<<<N_HID, 64, 0, stream>>>(fc1w, ln1g, ln1b, fc1b, modep + 1, Wp, u, v);
    k_cvt4   <<<(49152 + 255) / 256, 256, 0, stream>>>(c1rel, c1roo, c2rel, c2roo, modep + 1, cw);

    k_gemm1_mfma<<<(n + 127) / 128, 256, 0, stream>>>(x, modep + 1, Wp, u, v, h1, n);

    k_agg<<<(n + 3) / 4, 256, 0, stream>>>(rowoff, col, wgt, h1, agg1, n, e);
    k_conv_mfma<128><<<(n + 127) / 128, 256, 0, stream>>>(agg1, h1, cw, cw + 16384, c1bre, modep + 1, g1, n);

    k_agg<<<(n + 3) / 4, 256, 0, stream>>>(rowoff, col, wgt, g1, agg2, n, e);
    k_conv_mfma<64><<<(n + 127) / 128, 256, 0, stream>>>(agg2, g1, cw + 32768, cw + 40960, c2bre, modep + 1, g2, n);

    k_final<<<(n + 3) / 4, 256, 0, stream>>>(g2, ln2g, ln2b, fc2w, fc2b, modep + 1, d_out, n);
}